// Round 8
// baseline (257.607 us; speedup 1.0000x reference)
//
#include <hip/hip_runtime.h>
#include <cstdint>
#include <cstddef>

// Problem constants
#define BB 8
#define SS 2048
#define DD 512

typedef __attribute__((ext_vector_type(8))) short bf16x8;
typedef __attribute__((ext_vector_type(4))) float f32x4;

__device__ __forceinline__ unsigned short f2bf(float f) {
  unsigned int u = __builtin_bit_cast(unsigned int, f);
  u = (u + 0x7FFFu + ((u >> 16) & 1u)) >> 16;  // RNE
  return (unsigned short)u;
}
__device__ __forceinline__ float bf2f(unsigned short s) {
  return __builtin_bit_cast(float, ((unsigned int)s) << 16);
}

__device__ __forceinline__ void gload_lds16(const unsigned short* g, unsigned short* l) {
  __builtin_amdgcn_global_load_lds(
      (const __attribute__((address_space(1))) void*)g,
      (__attribute__((address_space(3))) void*)l, 16, 0, 0);
}

// ---------------------------------------------------------------------------
// 128x128-tile bf16 GEMM mainloop, BK=64, XOR-swizzled LDS.
// A[M,K] row-major, B[N,K] row-major (B^T input). 4 waves 2x2; per K-step:
// 16 ds_read_b128 + 32 MFMA + 8 global_load_lds (vs 8/16/4 at BK=32) and
// HALF the barrier count. LDS tiles [128][64] with 16B-slot swizzle
// slot' = slot ^ (row&7): staging uses linear dest + XOR'd per-lane SOURCE
// (rule 21), reads XOR the slot -> ~2-way banks instead of 8-way.
// Requires 64 KB LDS (lA 32K + lB 32K) -> 2 blocks/CU.
// ---------------------------------------------------------------------------
__device__ __forceinline__ void gemm_tile64(
    const unsigned short* __restrict__ A,
    const unsigned short* __restrict__ B,
    int K, unsigned short* lA, unsigned short* lB,
    f32x4 acc[4][4], size_t m0, size_t n0)
{
  const int t = threadIdx.x;
  const int l = t & 63;
  const int w = t >> 6;
  const int wr = w >> 1, wc = w & 1;

  // staging: round r covers rows r*32 + (t>>3); lane's linear dest slot is
  // (t&7), so its SOURCE col slot is (t&7) ^ (row&7)  [involution]
  const int srow = t >> 3;                          // 0..31
  const int scol = ((t & 7) ^ (srow & 7)) * 8;      // pre-swizzled source
  const unsigned short* gA = A + (m0 + (size_t)srow) * (size_t)K + scol;
  const unsigned short* gB = B + (n0 + (size_t)srow) * (size_t)K + scol;
  const size_t K32 = (size_t)K * 32;

  const int nk = K >> 6;
  int buf = 0;

  // prologue: stage k-tile 0 into buffer 0
#pragma unroll
  for (int r = 0; r < 4; ++r) {
    gload_lds16(gA + (size_t)r * K32, lA + r * 2048 + t * 8);
    gload_lds16(gB + (size_t)r * K32, lB + r * 2048 + t * 8);
  }

  for (int kt = 0; kt < nk; ++kt) {
    __syncthreads();  // stage(kt) complete (compiler drains vmcnt before barrier)
    if (kt + 1 < nk) {
      const int ko = (kt + 1) << 6;
      const int lo = (buf ^ 1) * 8192;
#pragma unroll
      for (int r = 0; r < 4; ++r) {
        gload_lds16(gA + ko + (size_t)r * K32, lA + lo + r * 2048 + t * 8);
        gload_lds16(gB + ko + (size_t)r * K32, lB + lo + r * 2048 + t * 8);
      }
    }
    const unsigned short* pa = lA + buf * 8192;
    const unsigned short* pb = lB + buf * 8192;
#pragma unroll
    for (int kk = 0; kk < 2; ++kk) {
      bf16x8 af[4], bfr[4];
#pragma unroll
      for (int m = 0; m < 4; ++m) {
        int row = wr * 64 + m * 16 + (l & 15);      // row&7 == l&7
        int slot = (kk * 4 + (l >> 4)) ^ (l & 7);
        af[m] = *(const bf16x8*)(pa + row * 64 + slot * 8);
      }
#pragma unroll
      for (int n = 0; n < 4; ++n) {
        int row = wc * 64 + n * 16 + (l & 15);
        int slot = (kk * 4 + (l >> 4)) ^ (l & 7);
        bfr[n] = *(const bf16x8*)(pb + row * 64 + slot * 8);
      }
#pragma unroll
      for (int m = 0; m < 4; ++m)
#pragma unroll
        for (int n = 0; n < 4; ++n)
          acc[m][n] = __builtin_amdgcn_mfma_f32_16x16x32_bf16(af[m], bfr[n], acc[m][n], 0, 0, 0);
    }
    buf ^= 1;
  }
}

// ---------------------------------------------------------------------------
// Packed bf16 epilogue: transpose through padded LDS ([128][136], rows 272 B
// = 17*16 so every chunk stays 16B-aligned and rows spread banks), then
// 8 coalesced bf16x8 stores/thread instead of 64 scattered 2B stores.
// Reuses the main-loop LDS (needs 17408 ushorts <= 32768).
// ---------------------------------------------------------------------------
__device__ __forceinline__ void store_bf16_tile(
    f32x4 acc[4][4], unsigned short* lds,
    unsigned short* __restrict__ Ct, size_t ldc, float scl)
{
  const int t = threadIdx.x, l = t & 63, w = t >> 6;
  const int wr = w >> 1, wc = w & 1;
  __syncthreads();  // main-loop LDS dead
#pragma unroll
  for (int m = 0; m < 4; ++m)
#pragma unroll
    for (int n = 0; n < 4; ++n)
#pragma unroll
      for (int j = 0; j < 4; ++j) {
        int row = wr * 64 + m * 16 + (l >> 4) * 4 + j;
        int col = wc * 64 + n * 16 + (l & 15);
        lds[row * 136 + col] = f2bf(acc[m][n][j] * scl);
      }
  __syncthreads();
  const int row = t >> 1;
  const int c0 = (t & 1) * 64;
#pragma unroll
  for (int i = 0; i < 8; ++i)
    *(bf16x8*)(Ct + (size_t)row * ldc + c0 + i * 8) =
        *(const bf16x8*)(lds + row * 136 + c0 + i * 8);
}

// ---------------------------------------------------------------------------
// Kernel 1: convert X and Wq|Wk|Wv fp32 -> bf16 (8 elems/thread).
// ---------------------------------------------------------------------------
__global__ __launch_bounds__(256) void convert_k(
    const float* __restrict__ X, const float* __restrict__ Wq,
    const float* __restrict__ Wk, const float* __restrict__ Wv,
    unsigned short* __restrict__ dst)
{
  const size_t NXe = (size_t)BB * SS * DD;  // 8388608
  const size_t NWe = (size_t)DD * DD;       // 262144
  size_t i = ((size_t)blockIdx.x * 256 + threadIdx.x) * 8;
  const float* src;
  size_t off;
  if (i < NXe)                { src = X;  off = i; }
  else if (i < NXe + NWe)     { src = Wq; off = i - NXe; }
  else if (i < NXe + 2 * NWe) { src = Wk; off = i - NXe - NWe; }
  else                        { src = Wv; off = i - NXe - 2 * NWe; }
  float4 f0 = *(const float4*)(src + off);
  float4 f1 = *(const float4*)(src + off + 4);
  bf16x8 o;
  o[0] = (short)f2bf(f0.x); o[1] = (short)f2bf(f0.y);
  o[2] = (short)f2bf(f0.z); o[3] = (short)f2bf(f0.w);
  o[4] = (short)f2bf(f1.x); o[5] = (short)f2bf(f1.y);
  o[6] = (short)f2bf(f1.z); o[7] = (short)f2bf(f1.w);
  *(bf16x8*)(dst + i) = o;
}

// ---------------------------------------------------------------------------
// Kernel 2: QKV projections. z=0 -> Q [16384,512] PRE-SCALED by 1/sqrt(S),
// z=1 -> K, z=2 -> V transposed per batch Vt[b][d][s] (packed via LDS).
// ---------------------------------------------------------------------------
__global__ __launch_bounds__(256, 2) void qkv_gemm_k(
    const unsigned short* __restrict__ Xb,
    const unsigned short* __restrict__ Wall,
    unsigned short* __restrict__ Qb,
    unsigned short* __restrict__ Kb,
    unsigned short* __restrict__ Vtb)
{
  __shared__ __align__(16) unsigned short sh[32768];  // 64 KB
  const int z = blockIdx.z;
  const unsigned short* Bw = Wall + (size_t)z * (DD * DD);
  const size_t m0 = (size_t)blockIdx.y * 128;
  const size_t n0 = (size_t)blockIdx.x * 128;
  f32x4 acc[4][4];
#pragma unroll
  for (int m = 0; m < 4; ++m)
#pragma unroll
    for (int n = 0; n < 4; ++n) acc[m][n] = (f32x4){0.f, 0.f, 0.f, 0.f};

  gemm_tile64(Xb, Bw, DD, sh, sh + 16384, acc, m0, n0);

  const int t = threadIdx.x, l = t & 63, w = t >> 6, wr = w >> 1, wc = w & 1;
  if (z < 2) {
    unsigned short* O = z ? Kb : Qb;
    const float sc = z ? 1.0f : 0.022097086912079608f;  // fold 1/sqrt(S) into Q
    store_bf16_tile(acc, sh, O + m0 * DD + n0, DD, sc);
  } else {
    // transposed pack: LDS laid out [d_local][s_local]
    __syncthreads();
#pragma unroll
    for (int m = 0; m < 4; ++m)
#pragma unroll
      for (int n = 0; n < 4; ++n)
#pragma unroll
        for (int j = 0; j < 4; ++j) {
          int row = wr * 64 + m * 16 + (l >> 4) * 4 + j;   // s_local
          int col = wc * 64 + n * 16 + (l & 15);           // d_local
          sh[col * 136 + row] = f2bf(acc[m][n][j]);
        }
    __syncthreads();
    const size_t bb = m0 >> 11;
    const size_t sBase = m0 & 2047;
    const int d = t >> 1;
    const int s0 = (t & 1) * 64;
    unsigned short* Vg = Vtb + (((bb * DD) + n0 + (size_t)d) << 11) + sBase;
#pragma unroll
    for (int i = 0; i < 8; ++i)
      *(bf16x8*)(Vg + s0 + i * 8) = *(const bf16x8*)(sh + d * 136 + s0 + i * 8);
  }
}

// ---------------------------------------------------------------------------
// Kernel 3: scores = Qs_b . K_b^T (pre-scaled) -> bf16 [b][2048][2048].
// Grid 1D 2048: b = lin&7 (batch <-> XCD), y-inner within batch.
// ---------------------------------------------------------------------------
__global__ __launch_bounds__(256, 2) void scores_gemm_k(
    const unsigned short* __restrict__ Qb,
    const unsigned short* __restrict__ Kb,
    unsigned short* __restrict__ Sc)
{
  __shared__ __align__(16) unsigned short sh[32768];
  const int lin = blockIdx.x;
  const int b = lin & 7;
  const int pos = lin >> 3;          // 0..255
  const int ty = pos & 15;           // q-row tile (inner)
  const int tx = pos >> 4;           // key tile (outer)
  const unsigned short* A  = Qb + (size_t)b * (SS * DD);
  const unsigned short* Bp = Kb + (size_t)b * (SS * DD);
  unsigned short* C = Sc + (size_t)b * ((size_t)SS * SS);
  const size_t m0 = (size_t)ty * 128;
  const size_t n0 = (size_t)tx * 128;
  f32x4 acc[4][4];
#pragma unroll
  for (int m = 0; m < 4; ++m)
#pragma unroll
    for (int n = 0; n < 4; ++n) acc[m][n] = (f32x4){0.f, 0.f, 0.f, 0.f};

  gemm_tile64(A, Bp, DD, sh, sh + 16384, acc, m0, n0);

  store_bf16_tile(acc, sh, C + m0 * SS + n0, SS, 1.0f);
}

// ---------------------------------------------------------------------------
// Kernel 4: in-place masked softmax over each score row (scores pre-scaled).
// ---------------------------------------------------------------------------
__global__ __launch_bounds__(256) void softmax_k(
    unsigned short* __restrict__ Sc, const int* __restrict__ mask)
{
  __shared__ float smax[4], ssum[4];
  const int row = blockIdx.x;          // 0..16383
  const int b = row >> 11;
  unsigned short* p = Sc + (size_t)row * SS;
  const int* mk = mask + ((size_t)b << 11);
  const int t = threadIdx.x;
  const int c0 = t * 8;

  bf16x8 sv = *(const bf16x8*)(p + c0);
  int4 ma = *(const int4*)(mk + c0);
  int4 mb = *(const int4*)(mk + c0 + 4);
  int mm[8] = {ma.x, ma.y, ma.z, ma.w, mb.x, mb.y, mb.z, mb.w};
  float v[8];
#pragma unroll
  for (int j = 0; j < 8; ++j) v[j] = bf2f((unsigned short)sv[j]);

  float mx = -3.0e38f;
#pragma unroll
  for (int j = 0; j < 8; ++j) if (mm[j]) mx = fmaxf(mx, v[j]);
#pragma unroll
  for (int off = 32; off >= 1; off >>= 1) mx = fmaxf(mx, __shfl_xor(mx, off));
  const int wid = t >> 6, ln = t & 63;
  if (ln == 0) smax[wid] = mx;
  __syncthreads();
  mx = fmaxf(fmaxf(smax[0], smax[1]), fmaxf(smax[2], smax[3]));

  float e[8];
  float sum = 0.f;
#pragma unroll
  for (int j = 0; j < 8; ++j) { e[j] = mm[j] ? __expf(v[j] - mx) : 0.f; sum += e[j]; }
#pragma unroll
  for (int off = 32; off >= 1; off >>= 1) sum += __shfl_xor(sum, off);
  if (ln == 0) ssum[wid] = sum;
  __syncthreads();
  sum = ssum[0] + ssum[1] + ssum[2] + ssum[3];
  const float inv = 1.f / sum;

  bf16x8 ov;
#pragma unroll
  for (int j = 0; j < 8; ++j) ov[j] = (short)f2bf(e[j] * inv);
  *(bf16x8*)(p + c0) = ov;
}

// ---------------------------------------------------------------------------
// Kernel 5: Out_b = P_b . V_b, fp32 output straight to d_out.
// Grid 1D 512: b = lin&7 (batch <-> XCD), x-inner within batch.
// ---------------------------------------------------------------------------
__global__ __launch_bounds__(256, 2) void pv_gemm_k(
    const unsigned short* __restrict__ Sc,
    const unsigned short* __restrict__ Vtb,
    float* __restrict__ Out)
{
  __shared__ __align__(16) unsigned short sh[32768];
  const int lin = blockIdx.x;
  const int b = lin & 7;
  const int pos = lin >> 3;          // 0..63
  const int tx = pos & 3;            // d tile (inner)
  const int ty = pos >> 2;           // q-row tile (outer)
  const unsigned short* A  = Sc + (size_t)b * ((size_t)SS * SS);
  const unsigned short* Bp = Vtb + (size_t)b * (DD * SS);
  float* C = Out + (size_t)b * (SS * DD);
  const size_t m0 = (size_t)ty * 128;
  const size_t n0 = (size_t)tx * 128;
  f32x4 acc[4][4];
#pragma unroll
  for (int m = 0; m < 4; ++m)
#pragma unroll
    for (int n = 0; n < 4; ++n) acc[m][n] = (f32x4){0.f, 0.f, 0.f, 0.f};

  gemm_tile64(A, Bp, SS, sh, sh + 16384, acc, m0, n0);

  const int t = threadIdx.x, l = t & 63, w = t >> 6, wr = w >> 1, wc = w & 1;
  const size_t rb = m0 + (size_t)(wr * 64 + ((l >> 4) * 4));
  const int cb = (int)n0 + wc * 64 + (l & 15);
#pragma unroll
  for (int m = 0; m < 4; ++m)
#pragma unroll
    for (int n = 0; n < 4; ++n)
#pragma unroll
      for (int j = 0; j < 4; ++j) {
        size_t r = rb + (size_t)(m * 16 + j);
        C[r * DD + (size_t)(cb + n * 16)] = acc[m][n][j];
      }
}

// ---------------------------------------------------------------------------
// Workspace layout (ushort elements):
//   Xb   @ 0         : 8388608   (bf16 X)
//   Wall @ 8388608   : 786432    (bf16 Wq|Wk|Wv)
//   Qb   @ 9175040   : 8388608   (pre-scaled by 1/sqrt(S))
//   Kb   @ 17563648  : 8388608
//   Vtb  @ 25952256  : 8388608   ([b][d][s])
//   Sc   @ 34340864  : 33554432  (scores -> probs, in place)
// ---------------------------------------------------------------------------
extern "C" void kernel_launch(void* const* d_in, const int* in_sizes, int n_in,
                              void* d_out, int out_size, void* d_ws, size_t ws_size,
                              hipStream_t stream) {
  const float* X    = (const float*)d_in[0];
  const int*   mask = (const int*)d_in[1];
  const float* Wq   = (const float*)d_in[2];
  const float* Wk   = (const float*)d_in[3];
  const float* Wv   = (const float*)d_in[4];

  unsigned short* ws   = (unsigned short*)d_ws;
  unsigned short* Xb   = ws;
  unsigned short* Wall = ws + 8388608;
  unsigned short* Qb   = ws + 9175040;
  unsigned short* Kb   = ws + 17563648;
  unsigned short* Vtb  = ws + 25952256;
  unsigned short* Sc   = ws + 34340864;
  float* Out = (float*)d_out;

  // 1) fp32 -> bf16 conversion of X and the three weight matrices
  convert_k<<<4480, 256, 0, stream>>>(X, Wq, Wk, Wv, ws);

  // 2) Q/K/V projections (z = 0/1/2); Q pre-scaled
  qkv_gemm_k<<<dim3(4, 128, 3), 256, 0, stream>>>(Xb, Wall, Qb, Kb, Vtb);

  // 3) scaled scores per batch (XCD-blocked)
  scores_gemm_k<<<2048, 256, 0, stream>>>(Qb, Kb, Sc);

  // 4) masked softmax in place
  softmax_k<<<16384, 256, 0, stream>>>(Sc, mask);

  // 5) probs . V -> fp32 output (XCD-blocked)
  pv_gemm_k<<<512, 256, 0, stream>>>(Sc, Vtb, Out);
}